// Round 8
// baseline (4989.404 us; speedup 1.0000x reference)
//
#include <hip/hip_runtime.h>
#include <cstdint>
#include <cstddef>

#define DEVI __device__ __forceinline__

typedef __attribute__((ext_vector_type(8))) short bf16x8;
typedef __attribute__((ext_vector_type(4))) float f32x4;
typedef unsigned short ushort_t;
typedef unsigned int uint_t;

// problem dims (fixed)
constexpr int NB = 64;    // batch
constexpr int NTT = 512;  // seq len
constexpr int NI = 512;   // input feat
constexpr int NH = 1024;  // hidden
constexpr int NA = 512;   // out feat
constexpr int NG = 4096;  // 4*NH
constexpr int CHUNK = 64; // scan chunk (timesteps per launch)

DEVI float bf2f(ushort_t u) { union { uint_t i; float f; } v; v.i = ((uint_t)u) << 16; return v.f; }
DEVI ushort_t f2bf(float f) {
  union { float f; uint_t i; } v; v.f = f;
  uint_t x = v.i;
  return (ushort_t)((x + 0x7fffu + ((x >> 16) & 1u)) >> 16);
}

// clamped fast tanh: safe for |x| large (clamp before exp), bf16-accurate
DEVI float tanh_f(float x) {
  x = fminf(fmaxf(x, -15.f), 15.f);
  float e = __expf(2.f * x);
  return (e - 1.f) / (e + 1.f);
}

DEVI void gload_lds16(const void* g, void* l) {
  __builtin_amdgcn_global_load_lds((__attribute__((address_space(1))) void*)g,
                                   (__attribute__((address_space(3))) void*)l, 16, 0, 0);
}

// ---------------- cast fp32 -> bf16 ----------------
__global__ __launch_bounds__(256) void cast_f32_bf16(const float* __restrict__ in,
                                                     ushort_t* __restrict__ out, int n) {
  int i = (blockIdx.x * 256 + threadIdx.x) * 4;
  if (i >= n) return;
  float4 v = *(const float4*)(in + i);
  ushort4 o;
  o.x = f2bf(v.x); o.y = f2bf(v.y); o.z = f2bf(v.z); o.w = f2bf(v.w);
  *(ushort4*)(out + i) = o;
}

// ---------------- generic NT GEMM: C[M,N] = A[M,K] * B[N,K]^T ----------------
template <int MODE>
__global__ __launch_bounds__(256) void gemm_nt(const short* __restrict__ A,
                                               const short* __restrict__ Bm,
                                               const float* __restrict__ bias0,
                                               const float* __restrict__ bias1,
                                               void* __restrict__ Cout,
                                               int M, int N, int K, int t0) {
  __shared__ short As[128 * 32];
  __shared__ short Bs[128 * 32];
  const int tid = threadIdx.x;
  const int wave = tid >> 6, lane = tid & 63;
  const int m0 = blockIdx.y * 128, n0 = blockIdx.x * 128;
  const int wr = wave >> 1, wc = wave & 1;

  f32x4 zero = {0.f, 0.f, 0.f, 0.f};
  f32x4 acc[4][4];
#pragma unroll
  for (int i = 0; i < 4; ++i)
#pragma unroll
    for (int j = 0; j < 4; ++j) acc[i][j] = zero;

  const int lrow = lane >> 2;
  const int lk = (lane & 3) * 8;

  for (int kt = 0; kt < K; kt += 32) {
#pragma unroll
    for (int c = 0; c < 2; ++c) {
      int q = wave + 4 * c;
      int row = m0 + q * 16 + lrow;
      long arow = (MODE == 2) ? ((long)(row >> 6) * NTT + t0 + (row & 63)) : (long)row;
      gload_lds16(A + arow * K + kt + lk, As + q * 512);
      gload_lds16(Bm + (long)(n0 + q * 16 + lrow) * K + kt + lk, Bs + q * 512);
    }
    __syncthreads();

    bf16x8 av[4], bv[4];
#pragma unroll
    for (int i = 0; i < 4; ++i) {
      int row = wr * 64 + i * 16 + (lane & 15);
      av[i] = *(const bf16x8*)(As + row * 32 + (lane >> 4) * 8);
    }
#pragma unroll
    for (int j = 0; j < 4; ++j) {
      int col = wc * 64 + j * 16 + (lane & 15);
      bv[j] = *(const bf16x8*)(Bs + col * 32 + (lane >> 4) * 8);
    }
#pragma unroll
    for (int i = 0; i < 4; ++i)
#pragma unroll
      for (int j = 0; j < 4; ++j)
        acc[i][j] = __builtin_amdgcn_mfma_f32_16x16x32_bf16(av[i], bv[j], acc[i][j], 0, 0, 0);
    __syncthreads();
  }

  const int fq = lane >> 4, fr = lane & 15;
#pragma unroll
  for (int i = 0; i < 4; ++i) {
#pragma unroll
    for (int j = 0; j < 4; ++j) {
      int gcol = n0 + wc * 64 + j * 16 + fr;
      float bsum = bias0[gcol];
      if (MODE == 2) bsum += bias1[gcol];
#pragma unroll
      for (int r = 0; r < 4; ++r) {
        int gm = m0 + wr * 64 + i * 16 + fq * 4 + r;
        float v = acc[i][j][r] + bsum;
        if (MODE == 0) {
          ((float*)Cout)[(long)gm * N + gcol] = v;
        } else if (MODE == 1) {
          ((ushort_t*)Cout)[(long)gm * N + gcol] = f2bf(tanhf(v));
        } else {
          int b = gm >> 6, tl = gm & 63;
          int wgp = (gcol >> 4) & 63, g = gcol >> 10, u = gcol & 15;
          ((ushort_t*)Cout)[((((long)tl * 64 + wgp) * 64 + b) << 6) + g * 16 + u] = f2bf(v);
        }
      }
    }
  }
}

// ---------------- persistent LSTM scan — probe variants ----------------
// REPB: barrier rounds/step; REPC: compute-phase reps; REPH: h-load reps.
// Extra reps are correctness-neutral (results sunk via asm volatile).
// Variant A(1,1,1) == R7 baseline structure.
template <int REPB, int REPC, int REPH>
__global__ __launch_bounds__(512, 2) void lstm_scan(const ushort_t* __restrict__ whh,
                                                    const ushort_t* __restrict__ gxc,  // [CHUNK][64][NB][64]
                                                    ushort_t* __restrict__ hseq,       // [CHUNK+1][NB][NH]
                                                    float* __restrict__ cbuf,          // [NB][NH]
                                                    ushort_t* __restrict__ hs,         // [NB][NTT][NH]
                                                    uint_t* __restrict__ flags,
                                                    int t0, uint_t tbase) {
  extern __shared__ char smem[];
  float* pre = (float*)(smem + 64 * NH * 2);  // [64][64] fp32 (16KB)
  const int wg = blockIdx.x, tid = threadIdx.x;
  const int wave = tid >> 6, lane = tid & 63;
  const int fq = lane >> 4, fr = lane & 15;
  const int g = wave >> 2, w2 = wave & 3;

  // stage weights into fragment-ordered LDS
  for (int idx = tid; idx < 64 * 128; idx += 512) {
    int n = idx >> 7, kc = idx & 127;
    int grow = (n >> 4) * NH + wg * 16 + (n & 15);
    bf16x8 w = *(const bf16x8*)(whh + (long)grow * NH + kc * 8);
    int frag = ((kc >> 2) * 4 + (n >> 4)) * 64 + (kc & 3) * 16 + (n & 15);
    *(bf16x8*)(smem + frag * 16) = w;
  }
  const int cb = tid >> 3, cup = tid & 7;
  float c0, c1;
  if (t0 == 0) {
    uint_t* p = (uint_t*)(hseq + cb * NH + wg * 16 + cup * 2);
    __hip_atomic_store(p, 0u, __ATOMIC_RELAXED, __HIP_MEMORY_SCOPE_AGENT);
    c0 = 0.f; c1 = 0.f;
  } else {
    c0 = cbuf[cb * NH + wg * 16 + cup * 2];
    c1 = cbuf[cb * NH + wg * 16 + cup * 2 + 1];
  }

  const int bb = w2 * 16;
  const int abrow = bb + fr;
  const int lane16 = lane * 16;
  f32x4 zero = {0.f, 0.f, 0.f, 0.f};

  ushort_t gxr[16];
  auto prefetch = [&](int tl) {
#pragma unroll
    for (int nt = 0; nt < 4; ++nt)
#pragma unroll
      for (int r = 0; r < 4; ++r)
        gxr[nt * 4 + r] =
            gxc[((((long)tl * 64 + wg) * 64 + (bb + fq * 4 + r)) << 6) + nt * 16 + fr];
  };
  auto poll = [&](uint_t t) {
    if (tid < 64) {
      uint_t* fp = flags + tid * 32;
      for (;;) {
        uint_t v = __hip_atomic_load(fp, __ATOMIC_RELAXED, __HIP_MEMORY_SCOPE_AGENT);
        if (__all(v >= t)) break;
        __builtin_amdgcn_s_sleep(1);
      }
    }
  };

  // initial barrier: weights staged, h slot0 + c ready
  asm volatile("s_waitcnt vmcnt(0)" ::: "memory");
  __syncthreads();
  if (tid == 0)
    __hip_atomic_store(flags + wg * 32, tbase + 1, __ATOMIC_RELAXED, __HIP_MEMORY_SCOPE_AGENT);
  poll(tbase + 1);
  __builtin_amdgcn_fence(__ATOMIC_ACQUIRE, "agent");
  __syncthreads();
  if (g == 0) prefetch(0);

  for (int tl = 0; tl < CHUNK; ++tl) {
    const ushort_t* hc = hseq + (size_t)tl * (NB * NH);

    // ---- PROBE D: extra warm h-load passes (issue 16, sink 16) ----
#pragma unroll
    for (int rep = 1; rep < REPH; ++rep) {
#pragma unroll
      for (int ks = 0; ks < 16; ++ks) {
        int ksg = g * 16 + ((ks + wg + rep) & 15);
        bf16x8 tt = *(const bf16x8*)(hc + abrow * NH + ksg * 32 + fq * 8);
        int4 ti = *(int4*)&tt;
        asm volatile("" ::"v"(ti.x), "v"(ti.y), "v"(ti.z), "v"(ti.w));
      }
    }

    // real h load (bulk, pinned)
    bf16x8 areg[16];
#pragma unroll
    for (int ks = 0; ks < 16; ++ks) {
      int ksg = g * 16 + ((ks + wg) & 15);
      areg[ks] = *(const bf16x8*)(hc + abrow * NH + ksg * 32 + fq * 8);
    }
    __builtin_amdgcn_sched_barrier(0);

    // ---- compute phase (PROBE C: repeated, extras sunk) ----
    f32x4 acc[4] = {zero, zero, zero, zero};
#pragma unroll
    for (int rep = 0; rep < REPC; ++rep) {
      f32x4 a2[4] = {zero, zero, zero, zero};
#pragma unroll
      for (int ks = 0; ks < 16; ++ks) {
        int ksg = g * 16 + ((ks + wg) & 15);
#pragma unroll
        for (int nt = 0; nt < 4; ++nt) {
          bf16x8 w = *(const bf16x8*)(smem + ((ksg * 4 + nt) << 10) + lane16);
          a2[nt] = __builtin_amdgcn_mfma_f32_16x16x32_bf16(areg[ks], w, a2[nt], 0, 0, 0);
        }
      }
      if (rep == 0) {
#pragma unroll
        for (int nt = 0; nt < 4; ++nt) acc[nt] = a2[nt];
      } else {
#pragma unroll
        for (int nt = 0; nt < 4; ++nt)
#pragma unroll
          for (int r = 0; r < 4; ++r) asm volatile("" ::"v"(a2[nt][r]));
      }
    }

    // combine K-half partials via pre[]
    if (g == 1) {
#pragma unroll
      for (int nt = 0; nt < 4; ++nt)
#pragma unroll
        for (int r = 0; r < 4; ++r)
          pre[(bb + fq * 4 + r) * 64 + nt * 16 + fr] = acc[nt][r];
    }
    __syncthreads();
    if (g == 0) {
#pragma unroll
      for (int nt = 0; nt < 4; ++nt)
#pragma unroll
        for (int r = 0; r < 4; ++r) {
          int ii = (bb + fq * 4 + r) * 64 + nt * 16 + fr;
          pre[ii] = pre[ii] + acc[nt][r] + bf2f(gxr[nt * 4 + r]);
        }
    }
    __syncthreads();
    // gates + state update for (cb, u0, u1)
    float h01[2];
#pragma unroll
    for (int k = 0; k < 2; ++k) {
      int u = cup * 2 + k;
      float xi = pre[cb * 64 + 0 * 16 + u];
      float xf = pre[cb * 64 + 1 * 16 + u];
      float xg = pre[cb * 64 + 2 * 16 + u];
      float xo = pre[cb * 64 + 3 * 16 + u];
      float ig = 1.f / (1.f + __expf(-xi));
      float fg = 1.f / (1.f + __expf(-xf));
      float gg = tanh_f(xg);
      float og = 1.f / (1.f + __expf(-xo));
      float& c = k ? c1 : c0;
      c = fg * c + ig * gg;
      h01[k] = og * tanh_f(c);
    }
    uint_t hpack = (uint_t)f2bf(h01[0]) | ((uint_t)f2bf(h01[1]) << 16);
    uint_t* hdst = (uint_t*)(hseq + (size_t)(tl + 1) * (NB * NH) + cb * NH + wg * 16 + cup * 2);
    __hip_atomic_store(hdst, hpack, __ATOMIC_RELAXED, __HIP_MEMORY_SCOPE_AGENT);
    if (tl == CHUNK - 1) {
      uint_t* h0 = (uint_t*)(hseq + cb * NH + wg * 16 + cup * 2);
      __hip_atomic_store(h0, hpack, __ATOMIC_RELAXED, __HIP_MEMORY_SCOPE_AGENT);
    }

    // ---- grid barrier (round 0: real, with payload release) ----
    asm volatile("s_waitcnt vmcnt(0)" ::: "memory");
    __syncthreads();
    uint_t t = tbase + 2 + (uint_t)tl * REPB;
    if (tid == 0)
      __hip_atomic_store(flags + wg * 32, t, __ATOMIC_RELAXED, __HIP_MEMORY_SCOPE_AGENT);
    *(uint_t*)(hs + ((size_t)cb * NTT + t0 + tl) * NH + wg * 16 + cup * 2) = hpack;
    if (g == 0 && tl + 1 < CHUNK) prefetch(tl + 1);
    poll(t);
    __syncthreads();
    // ---- PROBE B: extra barrier rounds ----
#pragma unroll
    for (int r = 1; r < REPB; ++r) {
      if (tid == 0)
        __hip_atomic_store(flags + wg * 32, t + r, __ATOMIC_RELAXED, __HIP_MEMORY_SCOPE_AGENT);
      poll(t + r);
      __syncthreads();
    }
    asm volatile("" ::: "memory");
  }
  cbuf[cb * NH + wg * 16 + cup * 2] = c0;
  cbuf[cb * NH + wg * 16 + cup * 2 + 1] = c1;
}

// ---------------- host ----------------
extern "C" void kernel_launch(void* const* d_in, const int* in_sizes, int n_in,
                              void* d_out, int out_size, void* d_ws, size_t ws_size,
                              hipStream_t stream) {
  const float* x = (const float*)d_in[0];
  const float* w1 = (const float*)d_in[1];
  const float* b1 = (const float*)d_in[2];
  const float* w_ih = (const float*)d_in[3];
  const float* w_hh = (const float*)d_in[4];
  const float* b_ih = (const float*)d_in[5];
  const float* b_hh = (const float*)d_in[6];
  const float* w3 = (const float*)d_in[7];
  const float* b3 = (const float*)d_in[8];

  char* ws = (char*)d_ws;
  size_t off = 0;
  auto alloc = [&](size_t bytes) {
    char* p = ws + off;
    off += (bytes + 255) & ~(size_t)255;
    return p;
  };
  ushort_t* w1b = (ushort_t*)alloc(sizeof(ushort_t) * NH * NI);
  ushort_t* wihb = (ushort_t*)alloc(sizeof(ushort_t) * NG * NH);
  ushort_t* whhb = (ushort_t*)alloc(sizeof(ushort_t) * NG * NH);
  ushort_t* w3b = (ushort_t*)alloc(sizeof(ushort_t) * NA * NH);
  ushort_t* fb = (ushort_t*)alloc(sizeof(ushort_t) * (size_t)NB * NTT * NH);
  float* cbuf = (float*)alloc(sizeof(float) * NB * NH);
  uint_t* flags = (uint_t*)alloc(sizeof(uint_t) * 64 * 32);
  if (off > ws_size) {
    hipMemsetAsync(d_out, 0xFF, 256, stream);
    return;
  }

  ushort_t* xb = (ushort_t*)d_out;
  ushort_t* hseq = (ushort_t*)d_out;                         // [CHUNK+1][NB][NH]
  ushort_t* gxc = (ushort_t*)d_out + (size_t)NB * NTT * NI;  // [CHUNK][64][NB][64]

  auto cast = [&](const float* src, ushort_t* dst, int n) {
    cast_f32_bf16<<<dim3((n / 4 + 255) / 256), dim3(256), 0, stream>>>(src, dst, n);
  };
  cast(x, xb, NB * NTT * NI);
  cast(w1, w1b, NH * NI);
  cast(w_ih, wihb, NG * NH);
  cast(w_hh, whhb, NG * NH);
  cast(w3, w3b, NA * NH);

  gemm_nt<1><<<dim3(NH / 128, NB * NTT / 128), dim3(256), 0, stream>>>(
      (const short*)xb, (const short*)w1b, b1, nullptr, fb, NB * NTT, NH, NI, 0);

  hipMemsetAsync(flags, 0, sizeof(uint_t) * 64 * 32, stream);
  int ldsz = 64 * NH * 2 + 64 * 64 * 4;
  hipFuncSetAttribute(reinterpret_cast<const void*>(&lstm_scan<1, 1, 1>),
                      hipFuncAttributeMaxDynamicSharedMemorySize, ldsz);
  hipFuncSetAttribute(reinterpret_cast<const void*>(&lstm_scan<3, 1, 1>),
                      hipFuncAttributeMaxDynamicSharedMemorySize, ldsz);
  hipFuncSetAttribute(reinterpret_cast<const void*>(&lstm_scan<1, 3, 1>),
                      hipFuncAttributeMaxDynamicSharedMemorySize, ldsz);
  hipFuncSetAttribute(reinterpret_cast<const void*>(&lstm_scan<1, 1, 3>),
                      hipFuncAttributeMaxDynamicSharedMemorySize, ldsz);

  for (int chunk = 0; chunk < NTT / CHUNK; ++chunk) {
    int t0 = chunk * CHUNK;
    gemm_nt<2><<<dim3(NG / 128, NB * CHUNK / 128), dim3(256), 0, stream>>>(
        (const short*)fb, (const short*)wihb, b_ih, b_hh, gxc, NB * CHUNK, NG, NH, t0);
    uint_t tb = (uint_t)(chunk * 264);
    switch (chunk & 3) {
      case 0:
        lstm_scan<1, 1, 1><<<dim3(64), dim3(512), ldsz, stream>>>(whhb, gxc, hseq, cbuf, fb, flags, t0, tb);
        break;
      case 1:
        lstm_scan<3, 1, 1><<<dim3(64), dim3(512), ldsz, stream>>>(whhb, gxc, hseq, cbuf, fb, flags, t0, tb);
        break;
      case 2:
        lstm_scan<1, 3, 1><<<dim3(64), dim3(512), ldsz, stream>>>(whhb, gxc, hseq, cbuf, fb, flags, t0, tb);
        break;
      default:
        lstm_scan<1, 1, 3><<<dim3(64), dim3(512), ldsz, stream>>>(whhb, gxc, hseq, cbuf, fb, flags, t0, tb);
        break;
    }
  }

  gemm_nt<0><<<dim3(NA / 128, NB * NTT / 128), dim3(256), 0, stream>>>(
      (const short*)fb, (const short*)w3b, b3, nullptr, d_out, NB * NTT, NA, NH, 0);
}

// Round 9
// 4287.706 us; speedup vs baseline: 1.1637x; 1.1637x over previous
//
#include <hip/hip_runtime.h>
#include <cstdint>
#include <cstddef>

#define DEVI __device__ __forceinline__

typedef __attribute__((ext_vector_type(8))) short bf16x8;
typedef __attribute__((ext_vector_type(4))) float f32x4;
typedef unsigned short ushort_t;
typedef unsigned int uint_t;

// problem dims (fixed)
constexpr int NB = 64;    // batch
constexpr int NTT = 512;  // seq len
constexpr int NI = 512;   // input feat
constexpr int NH = 1024;  // hidden
constexpr int NA = 512;   // out feat
constexpr int NG = 4096;  // 4*NH
constexpr int CHUNK = 64; // scan chunk (timesteps per launch)

DEVI float bf2f(ushort_t u) { union { uint_t i; float f; } v; v.i = ((uint_t)u) << 16; return v.f; }
DEVI ushort_t f2bf(float f) {
  union { float f; uint_t i; } v; v.f = f;
  uint_t x = v.i;
  return (ushort_t)((x + 0x7fffu + ((x >> 16) & 1u)) >> 16);
}

// clamped fast tanh: safe for |x| large (clamp before exp), bf16-accurate
DEVI float tanh_f(float x) {
  x = fminf(fmaxf(x, -15.f), 15.f);
  float e = __expf(2.f * x);
  return (e - 1.f) / (e + 1.f);
}

DEVI void gload_lds16(const void* g, void* l) {
  __builtin_amdgcn_global_load_lds((__attribute__((address_space(1))) void*)g,
                                   (__attribute__((address_space(3))) void*)l, 16, 0, 0);
}

// ---------------- cast fp32 -> bf16 ----------------
__global__ __launch_bounds__(256) void cast_f32_bf16(const float* __restrict__ in,
                                                     ushort_t* __restrict__ out, int n) {
  int i = (blockIdx.x * 256 + threadIdx.x) * 4;
  if (i >= n) return;
  float4 v = *(const float4*)(in + i);
  ushort4 o;
  o.x = f2bf(v.x); o.y = f2bf(v.y); o.z = f2bf(v.z); o.w = f2bf(v.w);
  *(ushort4*)(out + i) = o;
}

// ---------------- generic NT GEMM: C[M,N] = A[M,K] * B[N,K]^T ----------------
// MODE 0: fp32 out, +bias0 (fc3) | MODE 1: bf16 out, tanh (fc1) |
// MODE 2: chunked gx, scatter to gxc[tl][wg][b][g*16+u]
template <int MODE>
__global__ __launch_bounds__(256) void gemm_nt(const short* __restrict__ A,
                                               const short* __restrict__ Bm,
                                               const float* __restrict__ bias0,
                                               const float* __restrict__ bias1,
                                               void* __restrict__ Cout,
                                               int M, int N, int K, int t0) {
  __shared__ short As[128 * 32];
  __shared__ short Bs[128 * 32];
  const int tid = threadIdx.x;
  const int wave = tid >> 6, lane = tid & 63;
  const int m0 = blockIdx.y * 128, n0 = blockIdx.x * 128;
  const int wr = wave >> 1, wc = wave & 1;

  f32x4 zero = {0.f, 0.f, 0.f, 0.f};
  f32x4 acc[4][4];
#pragma unroll
  for (int i = 0; i < 4; ++i)
#pragma unroll
    for (int j = 0; j < 4; ++j) acc[i][j] = zero;

  const int lrow = lane >> 2;
  const int lk = (lane & 3) * 8;

  for (int kt = 0; kt < K; kt += 32) {
#pragma unroll
    for (int c = 0; c < 2; ++c) {
      int q = wave + 4 * c;
      int row = m0 + q * 16 + lrow;
      long arow = (MODE == 2) ? ((long)(row >> 6) * NTT + t0 + (row & 63)) : (long)row;
      gload_lds16(A + arow * K + kt + lk, As + q * 512);
      gload_lds16(Bm + (long)(n0 + q * 16 + lrow) * K + kt + lk, Bs + q * 512);
    }
    __syncthreads();

    bf16x8 av[4], bv[4];
#pragma unroll
    for (int i = 0; i < 4; ++i) {
      int row = wr * 64 + i * 16 + (lane & 15);
      av[i] = *(const bf16x8*)(As + row * 32 + (lane >> 4) * 8);
    }
#pragma unroll
    for (int j = 0; j < 4; ++j) {
      int col = wc * 64 + j * 16 + (lane & 15);
      bv[j] = *(const bf16x8*)(Bs + col * 32 + (lane >> 4) * 8);
    }
#pragma unroll
    for (int i = 0; i < 4; ++i)
#pragma unroll
      for (int j = 0; j < 4; ++j)
        acc[i][j] = __builtin_amdgcn_mfma_f32_16x16x32_bf16(av[i], bv[j], acc[i][j], 0, 0, 0);
    __syncthreads();
  }

  const int fq = lane >> 4, fr = lane & 15;
#pragma unroll
  for (int i = 0; i < 4; ++i) {
#pragma unroll
    for (int j = 0; j < 4; ++j) {
      int gcol = n0 + wc * 64 + j * 16 + fr;
      float bsum = bias0[gcol];
      if (MODE == 2) bsum += bias1[gcol];
#pragma unroll
      for (int r = 0; r < 4; ++r) {
        int gm = m0 + wr * 64 + i * 16 + fq * 4 + r;
        float v = acc[i][j][r] + bsum;
        if (MODE == 0) {
          ((float*)Cout)[(long)gm * N + gcol] = v;
        } else if (MODE == 1) {
          ((ushort_t*)Cout)[(long)gm * N + gcol] = f2bf(tanhf(v));
        } else {
          int b = gm >> 6, tl = gm & 63;
          int wgp = (gcol >> 4) & 63, g = gcol >> 10, u = gcol & 15;
          ((ushort_t*)Cout)[((((long)tl * 64 + wgp) * 64 + b) << 6) + g * 16 + u] = f2bf(v);
        }
      }
    }
  }
}

// ---------------- persistent LSTM scan (one chunk of CHUNK timesteps) ----------------
// R9: flags PACKED at 4B stride -> poll is one coalesced 256B read (2-4 LLC
// lines) instead of 64 scattered lines. Rest identical to R7 structure.
__global__ __launch_bounds__(512, 2) void lstm_scan(const ushort_t* __restrict__ whh,
                                                    const ushort_t* __restrict__ gxc,  // [CHUNK][64][NB][64]
                                                    ushort_t* __restrict__ hseq,       // [CHUNK+1][NB][NH]
                                                    float* __restrict__ cbuf,          // [NB][NH]
                                                    ushort_t* __restrict__ hs,         // [NB][NTT][NH]
                                                    uint_t* __restrict__ flags,        // [64] packed
                                                    int t0, uint_t tbase) {
  extern __shared__ char smem[];
  float* pre = (float*)(smem + 64 * NH * 2);  // [64][64] fp32 (16KB)
  const int wg = blockIdx.x, tid = threadIdx.x;
  const int wave = tid >> 6, lane = tid & 63;
  const int fq = lane >> 4, fr = lane & 15;
  const int g = wave >> 2, w2 = wave & 3;

  // stage weights into fragment-ordered LDS:
  // frag[(ksg*4+nt)*64 + fq*16 + fr] <- W[n=nt*16+fr][k=ksg*32+fq*8 ..+8]
  for (int idx = tid; idx < 64 * 128; idx += 512) {
    int n = idx >> 7, kc = idx & 127;
    int grow = (n >> 4) * NH + wg * 16 + (n & 15);
    bf16x8 w = *(const bf16x8*)(whh + (long)grow * NH + kc * 8);
    int frag = ((kc >> 2) * 4 + (n >> 4)) * 64 + (kc & 3) * 16 + (n & 15);
    *(bf16x8*)(smem + frag * 16) = w;
  }
  const int cb = tid >> 3, cup = tid & 7;  // thread owns (b=cb, u=2*cup, 2*cup+1)
  float c0, c1;
  if (t0 == 0) {
    uint_t* p = (uint_t*)(hseq + cb * NH + wg * 16 + cup * 2);
    __hip_atomic_store(p, 0u, __ATOMIC_RELAXED, __HIP_MEMORY_SCOPE_AGENT);
    c0 = 0.f; c1 = 0.f;
  } else {
    c0 = cbuf[cb * NH + wg * 16 + cup * 2];
    c1 = cbuf[cb * NH + wg * 16 + cup * 2 + 1];
  }

  const int bb = w2 * 16;          // batch base for this wave
  const int abrow = bb + fr;       // A-frag row (batch)
  const int lane16 = lane * 16;
  f32x4 zero = {0.f, 0.f, 0.f, 0.f};

  ushort_t gxr[16];
  auto prefetch = [&](int tl) {  // g==0 waves: all 64 n for own batches
#pragma unroll
    for (int nt = 0; nt < 4; ++nt)
#pragma unroll
      for (int r = 0; r < 4; ++r)
        gxr[nt * 4 + r] =
            gxc[((((long)tl * 64 + wg) * 64 + (bb + fq * 4 + r)) << 6) + nt * 16 + fr];
  };
  auto poll = [&](uint_t t) {
    if (tid < 64) {
      for (;;) {
        uint_t v = __hip_atomic_load(flags + tid, __ATOMIC_RELAXED, __HIP_MEMORY_SCOPE_AGENT);
        if (__all(v >= t)) break;
        __builtin_amdgcn_s_sleep(1);
      }
    }
  };

  // initial barrier: weights staged, h slot0 + c ready
  asm volatile("s_waitcnt vmcnt(0)" ::: "memory");
  __syncthreads();
  if (tid == 0)
    __hip_atomic_store(flags + wg, tbase + 1, __ATOMIC_RELAXED, __HIP_MEMORY_SCOPE_AGENT);
  poll(tbase + 1);
  // one agent acquire per chunk: drop stale L1/L2 lines of reused hseq slots
  __builtin_amdgcn_fence(__ATOMIC_ACQUIRE, "agent");
  __syncthreads();
  if (g == 0) prefetch(0);

  for (int tl = 0; tl < CHUNK; ++tl) {
    const ushort_t* hc = hseq + (size_t)tl * (NB * NH);
    // bulk-stage this wave's disjoint K-half slice: 16 x 16B loads in flight
    bf16x8 areg[16];
#pragma unroll
    for (int ks = 0; ks < 16; ++ks) {
      int ksg = g * 16 + ((ks + wg) & 15);  // per-WG rotation de-bursts LLC lines
      areg[ks] = *(const bf16x8*)(hc + abrow * NH + ksg * 32 + fq * 8);
    }
    __builtin_amdgcn_sched_barrier(0);

    f32x4 acc[4] = {zero, zero, zero, zero};
#pragma unroll
    for (int ks = 0; ks < 16; ++ks) {
      int ksg = g * 16 + ((ks + wg) & 15);
#pragma unroll
      for (int nt = 0; nt < 4; ++nt) {
        bf16x8 w = *(const bf16x8*)(smem + ((ksg * 4 + nt) << 10) + lane16);
        acc[nt] = __builtin_amdgcn_mfma_f32_16x16x32_bf16(areg[ks], w, acc[nt], 0, 0, 0);
      }
    }
    // combine K-half partials via pre[]
    if (g == 1) {
#pragma unroll
      for (int nt = 0; nt < 4; ++nt)
#pragma unroll
        for (int r = 0; r < 4; ++r)
          pre[(bb + fq * 4 + r) * 64 + nt * 16 + fr] = acc[nt][r];
    }
    __syncthreads();
    if (g == 0) {
#pragma unroll
      for (int nt = 0; nt < 4; ++nt)
#pragma unroll
        for (int r = 0; r < 4; ++r) {
          int ii = (bb + fq * 4 + r) * 64 + nt * 16 + fr;
          pre[ii] = pre[ii] + acc[nt][r] + bf2f(gxr[nt * 4 + r]);
        }
    }
    __syncthreads();
    // gates + state update for (cb, u0, u1)
    float h01[2];
#pragma unroll
    for (int k = 0; k < 2; ++k) {
      int u = cup * 2 + k;
      float xi = pre[cb * 64 + 0 * 16 + u];
      float xf = pre[cb * 64 + 1 * 16 + u];
      float xg = pre[cb * 64 + 2 * 16 + u];
      float xo = pre[cb * 64 + 3 * 16 + u];
      float ig = 1.f / (1.f + __expf(-xi));
      float fg = 1.f / (1.f + __expf(-xf));
      float gg = tanh_f(xg);
      float og = 1.f / (1.f + __expf(-xo));
      float& c = k ? c1 : c0;
      c = fg * c + ig * gg;
      h01[k] = og * tanh_f(c);
    }
    uint_t hpack = (uint_t)f2bf(h01[0]) | ((uint_t)f2bf(h01[1]) << 16);
    uint_t* hdst = (uint_t*)(hseq + (size_t)(tl + 1) * (NB * NH) + cb * NH + wg * 16 + cup * 2);
    __hip_atomic_store(hdst, hpack, __ATOMIC_RELAXED, __HIP_MEMORY_SCOPE_AGENT);
    if (tl == CHUNK - 1) {  // hand h(final) to next chunk's slot 0
      uint_t* h0 = (uint_t*)(hseq + cb * NH + wg * 16 + cup * 2);
      __hip_atomic_store(h0, hpack, __ATOMIC_RELAXED, __HIP_MEMORY_SCOPE_AGENT);
    }

    // ---- grid barrier: vmcnt-drain release, packed-flag poll ----
    asm volatile("s_waitcnt vmcnt(0)" ::: "memory");  // h atomic stores acked at LLC
    __syncthreads();
    uint_t t = tbase + 2 + tl;
    if (tid == 0)
      __hip_atomic_store(flags + wg, t, __ATOMIC_RELAXED, __HIP_MEMORY_SCOPE_AGENT);
    // off-critical-path work overlapped with the wait:
    *(uint_t*)(hs + ((size_t)cb * NTT + t0 + tl) * NH + wg * 16 + cup * 2) = hpack;
    if (g == 0 && tl + 1 < CHUNK) prefetch(tl + 1);
    poll(t);
    __syncthreads();
    asm volatile("" ::: "memory");
  }
  // persist c for next chunk
  cbuf[cb * NH + wg * 16 + cup * 2] = c0;
  cbuf[cb * NH + wg * 16 + cup * 2 + 1] = c1;
}

// ---------------- host ----------------
extern "C" void kernel_launch(void* const* d_in, const int* in_sizes, int n_in,
                              void* d_out, int out_size, void* d_ws, size_t ws_size,
                              hipStream_t stream) {
  const float* x = (const float*)d_in[0];
  const float* w1 = (const float*)d_in[1];
  const float* b1 = (const float*)d_in[2];
  const float* w_ih = (const float*)d_in[3];
  const float* w_hh = (const float*)d_in[4];
  const float* b_ih = (const float*)d_in[5];
  const float* b_hh = (const float*)d_in[6];
  const float* w3 = (const float*)d_in[7];
  const float* b3 = (const float*)d_in[8];

  char* ws = (char*)d_ws;
  size_t off = 0;
  auto alloc = [&](size_t bytes) {
    char* p = ws + off;
    off += (bytes + 255) & ~(size_t)255;
    return p;
  };
  ushort_t* w1b = (ushort_t*)alloc(sizeof(ushort_t) * NH * NI);
  ushort_t* wihb = (ushort_t*)alloc(sizeof(ushort_t) * NG * NH);
  ushort_t* whhb = (ushort_t*)alloc(sizeof(ushort_t) * NG * NH);
  ushort_t* w3b = (ushort_t*)alloc(sizeof(ushort_t) * NA * NH);
  ushort_t* fb = (ushort_t*)alloc(sizeof(ushort_t) * (size_t)NB * NTT * NH);  // f, then hs (in-place)
  float* cbuf = (float*)alloc(sizeof(float) * NB * NH);
  uint_t* flags = (uint_t*)alloc(sizeof(uint_t) * 64);
  if (off > ws_size) {
    hipMemsetAsync(d_out, 0xFF, 256, stream);  // NaN sentinel: ws too small
    return;
  }

  // scratch carved out of d_out (dead before fc3 writes d_out):
  ushort_t* xb = (ushort_t*)d_out;                           // bf16 x for fc1
  ushort_t* hseq = (ushort_t*)d_out;                         // [CHUNK+1][NB][NH] (reuses xb)
  ushort_t* gxc = (ushort_t*)d_out + (size_t)NB * NTT * NI;  // [CHUNK][64][NB][64]

  auto cast = [&](const float* src, ushort_t* dst, int n) {
    cast_f32_bf16<<<dim3((n / 4 + 255) / 256), dim3(256), 0, stream>>>(src, dst, n);
  };
  cast(x, xb, NB * NTT * NI);
  cast(w1, w1b, NH * NI);
  cast(w_ih, wihb, NG * NH);
  cast(w_hh, whhb, NG * NH);
  cast(w3, w3b, NA * NH);

  // fc1 + tanh -> f (bf16)
  gemm_nt<1><<<dim3(NH / 128, NB * NTT / 128), dim3(256), 0, stream>>>(
      (const short*)xb, (const short*)w1b, b1, nullptr, fb, NB * NTT, NH, NI, 0);

  hipMemsetAsync(flags, 0, sizeof(uint_t) * 64, stream);
  int ldsz = 64 * NH * 2 + 64 * 64 * 4;
  hipFuncSetAttribute(reinterpret_cast<const void*>(&lstm_scan),
                      hipFuncAttributeMaxDynamicSharedMemorySize, ldsz);

  for (int chunk = 0; chunk < NTT / CHUNK; ++chunk) {
    int t0 = chunk * CHUNK;
    gemm_nt<2><<<dim3(NG / 128, NB * CHUNK / 128), dim3(256), 0, stream>>>(
        (const short*)fb, (const short*)wihb, b_ih, b_hh, gxc, NB * CHUNK, NG, NH, t0);
    lstm_scan<<<dim3(64), dim3(512), ldsz, stream>>>(
        whhb, gxc, hseq, cbuf, fb, flags, t0, (uint_t)(chunk * (CHUNK + 1)));
  }

  // fc3 head -> d_out (fp32)
  gemm_nt<0><<<dim3(NA / 128, NB * NTT / 128), dim3(256), 0, stream>>>(
      (const short*)fb, (const short*)w3b, b3, nullptr, d_out, NB * NTT, NA, NH, 0);
}

// Round 10
// 4021.482 us; speedup vs baseline: 1.2407x; 1.0662x over previous
//
#include <hip/hip_runtime.h>
#include <cstdint>
#include <cstddef>

#define DEVI __device__ __forceinline__

typedef __attribute__((ext_vector_type(8))) short bf16x8;
typedef __attribute__((ext_vector_type(4))) float f32x4;
typedef unsigned short ushort_t;
typedef unsigned int uint_t;

// problem dims (fixed)
constexpr int NB = 64;    // batch
constexpr int NTT = 512;  // seq len
constexpr int NI = 512;   // input feat
constexpr int NH = 1024;  // hidden
constexpr int NA = 512;   // out feat
constexpr int NG = 4096;  // 4*NH
constexpr int CHUNK = 64; // scan chunk (timesteps per launch)

DEVI float bf2f(ushort_t u) { union { uint_t i; float f; } v; v.i = ((uint_t)u) << 16; return v.f; }
DEVI ushort_t f2bf(float f) {
  union { float f; uint_t i; } v; v.f = f;
  uint_t x = v.i;
  return (ushort_t)((x + 0x7fffu + ((x >> 16) & 1u)) >> 16);
}

// clamped fast tanh: safe for |x| large (clamp before exp), bf16-accurate
DEVI float tanh_f(float x) {
  x = fminf(fmaxf(x, -15.f), 15.f);
  float e = __expf(2.f * x);
  return (e - 1.f) / (e + 1.f);
}

DEVI void gload_lds16(const void* g, void* l) {
  __builtin_amdgcn_global_load_lds((__attribute__((address_space(1))) void*)g,
                                   (__attribute__((address_space(3))) void*)l, 16, 0, 0);
}

// ---------------- cast fp32 -> bf16 ----------------
__global__ __launch_bounds__(256) void cast_f32_bf16(const float* __restrict__ in,
                                                     ushort_t* __restrict__ out, int n) {
  int i = (blockIdx.x * 256 + threadIdx.x) * 4;
  if (i >= n) return;
  float4 v = *(const float4*)(in + i);
  ushort4 o;
  o.x = f2bf(v.x); o.y = f2bf(v.y); o.z = f2bf(v.z); o.w = f2bf(v.w);
  *(ushort4*)(out + i) = o;
}

// ---------------- generic NT GEMM: C[M,N] = A[M,K] * B[N,K]^T ----------------
// MODE 0: fp32 out, +bias0 (fc3) | MODE 1: bf16 out, tanh (fc1) |
// MODE 2: chunked gx, scatter to gxc[tl][wg][b][g*16+u]
template <int MODE>
__global__ __launch_bounds__(256) void gemm_nt(const short* __restrict__ A,
                                               const short* __restrict__ Bm,
                                               const float* __restrict__ bias0,
                                               const float* __restrict__ bias1,
                                               void* __restrict__ Cout,
                                               int M, int N, int K, int t0) {
  __shared__ short As[128 * 32];
  __shared__ short Bs[128 * 32];
  const int tid = threadIdx.x;
  const int wave = tid >> 6, lane = tid & 63;
  const int m0 = blockIdx.y * 128, n0 = blockIdx.x * 128;
  const int wr = wave >> 1, wc = wave & 1;

  f32x4 zero = {0.f, 0.f, 0.f, 0.f};
  f32x4 acc[4][4];
#pragma unroll
  for (int i = 0; i < 4; ++i)
#pragma unroll
    for (int j = 0; j < 4; ++j) acc[i][j] = zero;

  const int lrow = lane >> 2;
  const int lk = (lane & 3) * 8;

  for (int kt = 0; kt < K; kt += 32) {
#pragma unroll
    for (int c = 0; c < 2; ++c) {
      int q = wave + 4 * c;
      int row = m0 + q * 16 + lrow;
      long arow = (MODE == 2) ? ((long)(row >> 6) * NTT + t0 + (row & 63)) : (long)row;
      gload_lds16(A + arow * K + kt + lk, As + q * 512);
      gload_lds16(Bm + (long)(n0 + q * 16 + lrow) * K + kt + lk, Bs + q * 512);
    }
    __syncthreads();

    bf16x8 av[4], bv[4];
#pragma unroll
    for (int i = 0; i < 4; ++i) {
      int row = wr * 64 + i * 16 + (lane & 15);
      av[i] = *(const bf16x8*)(As + row * 32 + (lane >> 4) * 8);
    }
#pragma unroll
    for (int j = 0; j < 4; ++j) {
      int col = wc * 64 + j * 16 + (lane & 15);
      bv[j] = *(const bf16x8*)(Bs + col * 32 + (lane >> 4) * 8);
    }
#pragma unroll
    for (int i = 0; i < 4; ++i)
#pragma unroll
      for (int j = 0; j < 4; ++j)
        acc[i][j] = __builtin_amdgcn_mfma_f32_16x16x32_bf16(av[i], bv[j], acc[i][j], 0, 0, 0);
    __syncthreads();
  }

  const int fq = lane >> 4, fr = lane & 15;
#pragma unroll
  for (int i = 0; i < 4; ++i) {
#pragma unroll
    for (int j = 0; j < 4; ++j) {
      int gcol = n0 + wc * 64 + j * 16 + fr;
      float bsum = bias0[gcol];
      if (MODE == 2) bsum += bias1[gcol];
#pragma unroll
      for (int r = 0; r < 4; ++r) {
        int gm = m0 + wr * 64 + i * 16 + fq * 4 + r;
        float v = acc[i][j][r] + bsum;
        if (MODE == 0) {
          ((float*)Cout)[(long)gm * N + gcol] = v;
        } else if (MODE == 1) {
          ((ushort_t*)Cout)[(long)gm * N + gcol] = f2bf(tanhf(v));
        } else {
          int b = gm >> 6, tl = gm & 63;
          int wgp = (gcol >> 4) & 63, g = gcol >> 10, u = gcol & 15;
          ((ushort_t*)Cout)[((((long)tl * 64 + wgp) * 64 + b) << 6) + g * 16 + u] = f2bf(v);
        }
      }
    }
  }
}

// ---------------- persistent LSTM scan (one chunk of CHUNK timesteps) ----------------
// 64 WGs x 512 threads; WG owns 16 hidden units. Waves: g = K-half, w2 = batch group.
// R10: (1) flags at 16B stride (8/line: low store-serialization, 8x less poll
// congestion than 128B stride); (2) in-register gate epilogue: acc[nt][r] already
// holds all 4 gates (nt) of unit u=fr for batch bb+4fq+r -> g1 dumps partials to
// pre[65-stride], g0 combines + gates + shfl-pairs h into 4B agent stores.
__global__ __launch_bounds__(512, 2) void lstm_scan(const ushort_t* __restrict__ whh,
                                                    const ushort_t* __restrict__ gxc,  // [CHUNK][64][NB][64]
                                                    ushort_t* __restrict__ hseq,       // [CHUNK+1][NB][NH]
                                                    float* __restrict__ cbuf,          // [NB][NH]
                                                    ushort_t* __restrict__ hs,         // [NB][NTT][NH]
                                                    uint_t* __restrict__ flags,        // 16B stride
                                                    int t0, uint_t tbase) {
  extern __shared__ char smem[];
  float* pre = (float*)(smem + 64 * NH * 2);  // [64][65] fp32
  const int wg = blockIdx.x, tid = threadIdx.x;
  const int wave = tid >> 6, lane = tid & 63;
  const int fq = lane >> 4, fr = lane & 15;
  const int g = wave >> 2, w2 = wave & 3;

  // stage weights into fragment-ordered LDS:
  // frag[(ksg*4+nt)*64 + fq*16 + fr] <- W[n=nt*16+fr][k=ksg*32+fq*8 ..+8]
  for (int idx = tid; idx < 64 * 128; idx += 512) {
    int n = idx >> 7, kc = idx & 127;
    int grow = (n >> 4) * NH + wg * 16 + (n & 15);
    bf16x8 w = *(const bf16x8*)(whh + (long)grow * NH + kc * 8);
    int frag = ((kc >> 2) * 4 + (n >> 4)) * 64 + (kc & 3) * 16 + (n & 15);
    *(bf16x8*)(smem + frag * 16) = w;
  }
  const int bb = w2 * 16;          // batch base for this wave
  const int abrow = bb + fr;       // A-frag row (batch)
  const int lane16 = lane * 16;
  f32x4 zero = {0.f, 0.f, 0.f, 0.f};

  // h(t=-1)=0 init (any thread mapping; covers WG's [64 batches x 16 units])
  if (t0 == 0) {
    int cb = tid >> 3, cup = tid & 7;
    uint_t* p = (uint_t*)(hseq + cb * NH + wg * 16 + cup * 2);
    __hip_atomic_store(p, 0u, __ATOMIC_RELAXED, __HIP_MEMORY_SCOPE_AGENT);
  }
  // c-state: g0 lanes own (b=bb+4fq+r, u=fr)
  float cc[4];
  if (g == 0) {
#pragma unroll
    for (int r = 0; r < 4; ++r)
      cc[r] = (t0 == 0) ? 0.f : cbuf[(bb + fq * 4 + r) * NH + wg * 16 + fr];
  }

  ushort_t gxr[16];
  auto prefetch = [&](int tl) {  // g0 waves: gx for (b in own range, all 64 n)
#pragma unroll
    for (int nt = 0; nt < 4; ++nt)
#pragma unroll
      for (int r = 0; r < 4; ++r)
        gxr[nt * 4 + r] =
            gxc[((((long)tl * 64 + wg) * 64 + (bb + fq * 4 + r)) << 6) + nt * 16 + fr];
  };
  auto poll = [&](uint_t t) {
    if (tid < 64) {
      for (;;) {
        uint_t v = __hip_atomic_load(flags + tid * 4, __ATOMIC_RELAXED, __HIP_MEMORY_SCOPE_AGENT);
        if (__all(v >= t)) break;
        __builtin_amdgcn_s_sleep(1);
      }
    }
  };

  // initial barrier: weights staged, h slot0 + c ready
  asm volatile("s_waitcnt vmcnt(0)" ::: "memory");
  __syncthreads();
  if (tid == 0)
    __hip_atomic_store(flags + wg * 4, tbase + 1, __ATOMIC_RELAXED, __HIP_MEMORY_SCOPE_AGENT);
  poll(tbase + 1);
  // one agent acquire per chunk: drop stale L1/L2 lines of reused hseq slots
  __builtin_amdgcn_fence(__ATOMIC_ACQUIRE, "agent");
  __syncthreads();
  if (g == 0) prefetch(0);

  for (int tl = 0; tl < CHUNK; ++tl) {
    const ushort_t* hc = hseq + (size_t)tl * (NB * NH);
    // bulk-stage this wave's disjoint K-half slice: 16 x 16B loads in flight
    bf16x8 areg[16];
#pragma unroll
    for (int ks = 0; ks < 16; ++ks) {
      int ksg = g * 16 + ((ks + wg) & 15);  // per-WG rotation de-bursts LLC lines
      areg[ks] = *(const bf16x8*)(hc + abrow * NH + ksg * 32 + fq * 8);
    }
    __builtin_amdgcn_sched_barrier(0);

    f32x4 acc[4] = {zero, zero, zero, zero};
#pragma unroll
    for (int ks = 0; ks < 16; ++ks) {
      int ksg = g * 16 + ((ks + wg) & 15);
#pragma unroll
      for (int nt = 0; nt < 4; ++nt) {
        bf16x8 w = *(const bf16x8*)(smem + ((ksg * 4 + nt) << 10) + lane16);
        acc[nt] = __builtin_amdgcn_mfma_f32_16x16x32_bf16(areg[ks], w, acc[nt], 0, 0, 0);
      }
    }
    // g1 dumps K-half partials
    if (g == 1) {
#pragma unroll
      for (int nt = 0; nt < 4; ++nt)
#pragma unroll
        for (int r = 0; r < 4; ++r)
          pre[(bb + fq * 4 + r) * 65 + nt * 16 + fr] = acc[nt][r];
    }
    __syncthreads();

    // g0: combine + gates fully in-register (gate = nt, unit = fr, batch = bb+4fq+r)
    uint_t hp[4];
    if (g == 0) {
#pragma unroll
      for (int r = 0; r < 4; ++r) {
        int b = bb + fq * 4 + r;
        float xi = pre[b * 65 + fr] + acc[0][r] + bf2f(gxr[r]);
        float xf = pre[b * 65 + 16 + fr] + acc[1][r] + bf2f(gxr[4 + r]);
        float xg = pre[b * 65 + 32 + fr] + acc[2][r] + bf2f(gxr[8 + r]);
        float xo = pre[b * 65 + 48 + fr] + acc[3][r] + bf2f(gxr[12 + r]);
        float ig = 1.f / (1.f + __expf(-xi));
        float fg = 1.f / (1.f + __expf(-xf));
        float gg = tanh_f(xg);
        float og = 1.f / (1.f + __expf(-xo));
        cc[r] = fg * cc[r] + ig * gg;
        float hv = og * tanh_f(cc[r]);
        uint_t hb = (uint_t)f2bf(hv);
        uint_t other = (uint_t)__shfl_xor((int)hb, 1, 64);  // pair units fr<->fr^1
        hp[r] = hb | (other << 16);                          // valid on even fr
        if (!(fr & 1)) {
          uint_t* hdst = (uint_t*)(hseq + (size_t)(tl + 1) * (NB * NH) + b * NH + wg * 16 + fr);
          __hip_atomic_store(hdst, hp[r], __ATOMIC_RELAXED, __HIP_MEMORY_SCOPE_AGENT);
          if (tl == CHUNK - 1) {  // hand h(final) to next chunk's slot 0
            uint_t* h0 = (uint_t*)(hseq + b * NH + wg * 16 + fr);
            __hip_atomic_store(h0, hp[r], __ATOMIC_RELAXED, __HIP_MEMORY_SCOPE_AGENT);
          }
        }
      }
    }

    // ---- grid barrier: vmcnt-drain release, 16B-stride flags ----
    asm volatile("s_waitcnt vmcnt(0)" ::: "memory");  // h agent-stores acked at LLC
    __syncthreads();
    uint_t t = tbase + 2 + tl;
    if (tid == 0)
      __hip_atomic_store(flags + wg * 4, t, __ATOMIC_RELAXED, __HIP_MEMORY_SCOPE_AGENT);
    // off-critical-path work overlapped with the wait:
    if (g == 0) {
      if (!(fr & 1)) {
#pragma unroll
        for (int r = 0; r < 4; ++r)
          *(uint_t*)(hs + ((size_t)(bb + fq * 4 + r) * NTT + t0 + tl) * NH + wg * 16 + fr) = hp[r];
      }
      if (tl + 1 < CHUNK) prefetch(tl + 1);
    }
    poll(t);
    __syncthreads();
    asm volatile("" ::: "memory");
  }
  // persist c for next chunk
  if (g == 0) {
#pragma unroll
    for (int r = 0; r < 4; ++r)
      cbuf[(bb + fq * 4 + r) * NH + wg * 16 + fr] = cc[r];
  }
}

// ---------------- host ----------------
extern "C" void kernel_launch(void* const* d_in, const int* in_sizes, int n_in,
                              void* d_out, int out_size, void* d_ws, size_t ws_size,
                              hipStream_t stream) {
  const float* x = (const float*)d_in[0];
  const float* w1 = (const float*)d_in[1];
  const float* b1 = (const float*)d_in[2];
  const float* w_ih = (const float*)d_in[3];
  const float* w_hh = (const float*)d_in[4];
  const float* b_ih = (const float*)d_in[5];
  const float* b_hh = (const float*)d_in[6];
  const float* w3 = (const float*)d_in[7];
  const float* b3 = (const float*)d_in[8];

  char* ws = (char*)d_ws;
  size_t off = 0;
  auto alloc = [&](size_t bytes) {
    char* p = ws + off;
    off += (bytes + 255) & ~(size_t)255;
    return p;
  };
  ushort_t* w1b = (ushort_t*)alloc(sizeof(ushort_t) * NH * NI);
  ushort_t* wihb = (ushort_t*)alloc(sizeof(ushort_t) * NG * NH);
  ushort_t* whhb = (ushort_t*)alloc(sizeof(ushort_t) * NG * NH);
  ushort_t* w3b = (ushort_t*)alloc(sizeof(ushort_t) * NA * NH);
  ushort_t* fb = (ushort_t*)alloc(sizeof(ushort_t) * (size_t)NB * NTT * NH);  // f, then hs (in-place)
  float* cbuf = (float*)alloc(sizeof(float) * NB * NH);
  uint_t* flags = (uint_t*)alloc(sizeof(uint_t) * 64 * 4);
  if (off > ws_size) {
    hipMemsetAsync(d_out, 0xFF, 256, stream);  // NaN sentinel: ws too small
    return;
  }

  // scratch carved out of d_out (dead before fc3 writes d_out):
  ushort_t* xb = (ushort_t*)d_out;                           // bf16 x for fc1
  ushort_t* hseq = (ushort_t*)d_out;                         // [CHUNK+1][NB][NH] (reuses xb)
  ushort_t* gxc = (ushort_t*)d_out + (size_t)NB * NTT * NI;  // [CHUNK][64][NB][64]

  auto cast = [&](const float* src, ushort_t* dst, int n) {
    cast_f32_bf16<<<dim3((n / 4 + 255) / 256), dim3(256), 0, stream>>>(src, dst, n);
  };
  cast(x, xb, NB * NTT * NI);
  cast(w1, w1b, NH * NI);
  cast(w_ih, wihb, NG * NH);
  cast(w_hh, whhb, NG * NH);
  cast(w3, w3b, NA * NH);

  // fc1 + tanh -> f (bf16)
  gemm_nt<1><<<dim3(NH / 128, NB * NTT / 128), dim3(256), 0, stream>>>(
      (const short*)xb, (const short*)w1b, b1, nullptr, fb, NB * NTT, NH, NI, 0);

  hipMemsetAsync(flags, 0, sizeof(uint_t) * 64 * 4, stream);
  int ldsz = 64 * NH * 2 + 64 * 65 * 4;
  hipFuncSetAttribute(reinterpret_cast<const void*>(&lstm_scan),
                      hipFuncAttributeMaxDynamicSharedMemorySize, ldsz);

  for (int chunk = 0; chunk < NTT / CHUNK; ++chunk) {
    int t0 = chunk * CHUNK;
    gemm_nt<2><<<dim3(NG / 128, NB * CHUNK / 128), dim3(256), 0, stream>>>(
        (const short*)fb, (const short*)wihb, b_ih, b_hh, gxc, NB * CHUNK, NG, NH, t0);
    lstm_scan<<<dim3(64), dim3(512), ldsz, stream>>>(
        whhb, gxc, hseq, cbuf, fb, flags, t0, (uint_t)(chunk * (CHUNK + 1)));
  }

  // fc3 head -> d_out (fp32)
  gemm_nt<0><<<dim3(NA / 128, NB * NTT / 128), dim3(256), 0, stream>>>(
      (const short*)fb, (const short*)w3b, b3, nullptr, d_out, NB * NTT, NA, NH, 0);
}